// Round 1
// baseline (3112.716 us; speedup 1.0000x reference)
//
#include <hip/hip_runtime.h>
#include <stdint.h>

// Problem constants (fixed by setup_inputs)
constexpr int Bn = 32, Cc = 24, Hh = 28, Ww = 28;
constexpr int OHt = 24, OWt = 24;           // output spatial
constexpr int CF = 600, HN = 128, TT = 96;  // channels-folded, hidden, spikes
constexpr int NPIX = OHt * OWt;             // 576
constexpr int NSAMP = Bn * TT * NPIX;       // 1,769,472
constexpr int NLOG = Bn * Cc * Hh * Ww;     // 602,112

// ---- JAX threefry2x32, key(42) -> (0, 42), partitionable counter mode ----
// out32(i) = x0' ^ x1' of threefry2x32((0,42), (hi32(i)=0, lo32(i)=i))
__device__ __forceinline__ uint32_t threefry_0_42(uint32_t x1) {
  const uint32_t ks1 = 42u, ks2 = 0x1BD11BF0u;  // 0x1BD11BDA ^ 0 ^ 42
  uint32_t x0 = 0u;        // x0 += ks0 (=0)
  x1 += ks1;
#define TF_RND(r) { x0 += x1; x1 = (x1 << (r)) | (x1 >> (32 - (r))); x1 ^= x0; }
  TF_RND(13) TF_RND(15) TF_RND(26) TF_RND(6)
  x0 += ks1; x1 += ks2 + 1u;
  TF_RND(17) TF_RND(29) TF_RND(16) TF_RND(24)
  x0 += ks2; x1 += 0u + 2u;
  TF_RND(13) TF_RND(15) TF_RND(26) TF_RND(6)
  x0 += 0u; x1 += ks1 + 3u;
  TF_RND(17) TF_RND(29) TF_RND(16) TF_RND(24)
  x0 += ks1; x1 += ks2 + 4u;
  TF_RND(13) TF_RND(15) TF_RND(26) TF_RND(6)
  x0 += ks2; x1 += 0u + 5u;
#undef TF_RND
  return x0 ^ x1;
}

// jax.random.gumbel: u = uniform(minval=FLT_MIN, maxval=1); g = -log(-log(u))
__device__ __forceinline__ float gumbel_at(uint32_t idx) {
  uint32_t bits = threefry_0_42(idx);
  float f = __uint_as_float((bits >> 9) | 0x3f800000u) - 1.0f;
  float u = (f == 0.0f) ? 1.17549435e-38f : f;  // max(tiny, f*1.0f + tiny)
  return -logf(-logf(u));
}

__global__ __launch_bounds__(256) void k_log(const float* __restrict__ in,
                                             float* __restrict__ lp) {
  int i = blockIdx.x * 256 + threadIdx.x;
  if (i < NLOG) lp[i] = logf(in[i]);
}

// One thread per sample (b,t,x,y): argmax over 600 gumbel+logit, first-max wins.
__global__ __launch_bounds__(256) void k_sample(const float* __restrict__ logp,
                                                int* __restrict__ spikes) {
  int sid = blockIdx.x * 256 + threadIdx.x;
  if (sid >= NSAMP) return;
  int y = sid % OWt;
  int x = (sid / OWt) % OHt;
  int b = sid / (NPIX * TT);
  uint32_t base = (uint32_t)sid * 600u;  // flat gumbel index base (< 2^32)
  const float* lpb = logp + (b * Cc) * (Hh * Ww) + x * Ww + y;
  float best = -1e30f;
  int bi = 0;
  int cf = 0;
  for (int c = 0; c < Cc; ++c) {
    const float* lpc = lpb + c * (Hh * Ww);
    for (int ki = 0; ki < 5; ++ki) {
      #pragma unroll
      for (int kj = 0; kj < 5; ++kj) {
        float v = gumbel_at(base + (uint32_t)cf) + lpc[ki * Ww + kj];
        if (v > best) { best = v; bi = cf; }
        ++cf;
      }
    }
  }
  spikes[sid] = bi;
}

// One wave per pixel, 2 neurons per lane; 96 sequential normalized updates.
__global__ __launch_bounds__(256) void k_recur(
    const int* __restrict__ spikes, const float* __restrict__ weights,
    const float* __restrict__ eps_xy, const float* __restrict__ eps_t,
    const float* __restrict__ eps0p, const float* __restrict__ h_init,
    float* __restrict__ out) {
  int wid = blockIdx.x * 4 + (threadIdx.x >> 6);  // pixel id in [0, 18432)
  int lane = threadIdx.x & 63;
  int y = wid % OWt;
  int x = (wid / OWt) % OHt;
  int b = wid / NPIX;
  float g0 = h_init[lane];
  float g1 = h_init[lane + 64];
  float e0 = eps0p[0];
  const int* sp = spikes + (b * TT) * NPIX + x * OWt + y;
  const float* ex = eps_xy + (x * OWt + y) * 25;
  for (int t = 0; t < TT; ++t) {
    int s = sp[t * NPIX];  // wave-uniform
    const float* wr = weights + s * HN;
    float wg0 = wr[lane] * g0;
    float wg1 = wr[lane + 64] * g1;
    float sum = wg0 + wg1;
    #pragma unroll
    for (int off = 32; off > 0; off >>= 1) sum += __shfl_xor(sum, off, 64);
    float es = ex[s % 25] * (eps_t[t] * e0);  // eps * (et * eps0)
    float factor = es / sum;
    if (!__builtin_isfinite(factor)) factor = 0.0f;  // nan_to_num
    float d = 1.0f + es;
    g0 = (g0 + wg0 * factor) / d;
    g1 = (g1 + wg1 * factor) / d;
  }
  out[((b * HN + lane) * OHt + x) * OWt + y] = g0;
  out[((b * HN + lane + 64) * OHt + x) * OWt + y] = g1;
}

extern "C" void kernel_launch(void* const* d_in, const int* in_sizes, int n_in,
                              void* d_out, int out_size, void* d_ws, size_t ws_size,
                              hipStream_t stream) {
  const float* input   = (const float*)d_in[0];
  const float* eps_xy  = (const float*)d_in[1];
  const float* eps0    = (const float*)d_in[2];
  const float* eps_t   = (const float*)d_in[3];
  const float* weights = (const float*)d_in[4];
  const float* h_init  = (const float*)d_in[5];
  // d_in[6] = number_of_spikes (=96, hardcoded)

  float* logp = (float*)d_ws;                                // 602,112 f32
  int* spikes = (int*)((char*)d_ws + NLOG * sizeof(float));  // 1,769,472 i32

  k_log<<<(NLOG + 255) / 256, 256, 0, stream>>>(input, logp);
  k_sample<<<NSAMP / 256, 256, 0, stream>>>(logp, spikes);
  k_recur<<<(Bn * NPIX) / 4, 256, 0, stream>>>(spikes, weights, eps_xy, eps_t,
                                               eps0, h_init, (float*)d_out);
}